// Round 21
// baseline (100.549 us; speedup 1.0000x reference)
//
#include <hip/hip_runtime.h>

// SNN classifier: T=500, B=256, 96 -> 64 -> 80, leaky (subtract reset).
// f32 BLAS-order arithmetic replicated exactly -> outputs bitwise-identical
// to the passing round-2..20 kernels.
//
// Round-21: R20's P=4 was neutral: stride-24 xs rows (gcd(24,32)=8) caused
// 896K bank conflicts, and 8 waves/CU left DS+VALU additive (48us = sum of
// the two ~20us floors). Verdict across R11/R16/R17/R20: occupancy beats P
// beyond P=2. This round hits the one untested point: P=2 + k-chunked
// double-buffer + CONFLICT-FREE stride 28 (gcd=4 class, measured-clean)
// -> 52KB LDS -> 3 blocks/CU = 12 waves (1.5x R16's hiding at equal P).
// Four 24-k chunks, stage-next-first, one barrier/chunk (covered by the
// co-resident blocks). k ascends across chunks -> bit-identical.
// K2/K3/K4 = R19 verbatim. Decision rule: >=97us -> revert K1, plateau.

#define T_STEPS 500
#define BATCH   256
#define N_IN    96
#define N_HID   64
#define N_OUT   80
#define CH      50    // chunk size in K2/K4 (500 = 10*50)
#define MASK_OFF 8192000  // float offset of mask region inside outs

// ---------------- K1: cur1 = x @ W1 + b1 ----------------
// grid 250*4, block 256 (4 waves = 4 h-quarters). Block = (t-pair, 64-b).
// LDS 52KB: xs buf0 @0, buf1 @3584 (each 2t*64b rows x 28 stride, 24k
// chunk), W1 @7168 ([96][64]). Epilogue reuses @0/@4352 for transposes.
__global__ __launch_bounds__(256) void k1_cur1(
    const float* __restrict__ x,   // (T,B,96)
    const float* __restrict__ W1,  // (96,64)
    const float* __restrict__ b1,  // (64)
    float* __restrict__ cur1)      // (T,B,64) region inside outs
{
    const int tp   = blockIdx.x >> 2;        // 0..249
    const int b0   = (blockIdx.x & 3) << 6;
    const int t0   = tp * 2;
    const int lane = threadIdx.x & 63;       // = local b
    const int w    = threadIdx.x >> 6;       // wave id = h-quarter
    const int o0   = w << 4;

    __shared__ float sm[13312];              // 52 KB
    const int XS0 = 0, XS1 = 3584, WS = 7168;

    // ---- stage W1 (once) + x chunk 0 into buf0
    {
        const float4* __restrict__ srcw = reinterpret_cast<const float4*>(W1);
        #pragma unroll
        for (int ii = 0; ii < 6; ++ii) {
            const int i = ii * 256 + threadIdx.x;
            *reinterpret_cast<float4*>(&sm[WS + i * 4]) = srcw[i];
        }
        #pragma unroll
        for (int ii = 0; ii < 3; ++ii) {
            const int i   = ii * 256 + threadIdx.x;   // 768 granules
            const int row = i / 6, g = i % 6;         // row = p*64+bb
            const int p   = row >> 6, bb = row & 63;
            const float4 v = *reinterpret_cast<const float4*>(
                x + ((size_t)(t0 + p) * BATCH + b0 + bb) * N_IN + g * 4);
            *reinterpret_cast<float4*>(&sm[XS0 + row * 28 + g * 4]) = v;
        }
    }
    __syncthreads();

    float acc0[16], acc1[16];
    #pragma unroll
    for (int o = 0; o < 16; ++o) { acc0[o] = 0.0f; acc1[o] = 0.0f; }

    #pragma unroll 1
    for (int c = 0; c < 4; ++c) {            // four 24-k chunks, k ascending
        const int rd  = (c & 1) ? XS1 : XS0;
        const int wr_ = (c & 1) ? XS0 : XS1;

        // ---- stage chunk c+1 (source-first: loads hoist above the FMAs)
        if (c < 3) {
            #pragma unroll
            for (int ii = 0; ii < 3; ++ii) {
                const int i   = ii * 256 + threadIdx.x;
                const int row = i / 6, g = i % 6;
                const int p   = row >> 6, bb = row & 63;
                const float4 v = *reinterpret_cast<const float4*>(
                    x + ((size_t)(t0 + p) * BATCH + b0 + bb) * N_IN
                      + (c + 1) * 24 + g * 4);
                *reinterpret_cast<float4*>(&sm[wr_ + row * 28 + g * 4]) = v;
            }
        }

        // ---- compute chunk c (DS-only inner loop, conflict-free stride 28)
        #pragma unroll
        for (int kg = 0; kg < 6; ++kg) {
            const float4 xv0 = *reinterpret_cast<const float4*>(
                &sm[rd + (0 * 64 + lane) * 28 + kg * 4]);
            const float4 xv1 = *reinterpret_cast<const float4*>(
                &sm[rd + (1 * 64 + lane) * 28 + kg * 4]);
            const float xq0[4] = {xv0.x, xv0.y, xv0.z, xv0.w};
            const float xq1[4] = {xv1.x, xv1.y, xv1.z, xv1.w};
            #pragma unroll
            for (int jj = 0; jj < 4; ++jj) {
                const int k = c * 24 + kg * 4 + jj;
                const float4* __restrict__ wvp =            // LDS broadcast
                    reinterpret_cast<const float4*>(&sm[WS + k * 64 + o0]);
                const float4 w0 = wvp[0], w1 = wvp[1], w2 = wvp[2], w3 = wvp[3];
                const float wv[16] = {w0.x, w0.y, w0.z, w0.w,
                                      w1.x, w1.y, w1.z, w1.w,
                                      w2.x, w2.y, w2.z, w2.w,
                                      w3.x, w3.y, w3.z, w3.w};
                const float xs0 = xq0[jj], xs1 = xq1[jj];
                #pragma unroll
                for (int o = 0; o < 16; ++o) {
                    acc0[o] = __fmaf_rn(xs0, wv[o], acc0[o]);
                    acc1[o] = __fmaf_rn(xs1, wv[o], acc1[o]);
                }
            }
        }
        __syncthreads();   // buf[c+1] staged AND this chunk's reads done
    }

    // ---- bias, transpose both t's via LDS (clobbers x/W areas), linear stores
    #pragma unroll
    for (int o4 = 0; o4 < 4; ++o4) {
        float4 v0, v1;
        v0.x = __fadd_rn(acc0[o4 * 4 + 0], b1[o0 + o4 * 4 + 0]);
        v0.y = __fadd_rn(acc0[o4 * 4 + 1], b1[o0 + o4 * 4 + 1]);
        v0.z = __fadd_rn(acc0[o4 * 4 + 2], b1[o0 + o4 * 4 + 2]);
        v0.w = __fadd_rn(acc0[o4 * 4 + 3], b1[o0 + o4 * 4 + 3]);
        v1.x = __fadd_rn(acc1[o4 * 4 + 0], b1[o0 + o4 * 4 + 0]);
        v1.y = __fadd_rn(acc1[o4 * 4 + 1], b1[o0 + o4 * 4 + 1]);
        v1.z = __fadd_rn(acc1[o4 * 4 + 2], b1[o0 + o4 * 4 + 2]);
        v1.w = __fadd_rn(acc1[o4 * 4 + 3], b1[o0 + o4 * 4 + 3]);
        *reinterpret_cast<float4*>(&sm[lane * 68 + o0 + o4 * 4]) = v0;
        *reinterpret_cast<float4*>(&sm[4352 + lane * 68 + o0 + o4 * 4]) = v1;
    }
    __syncthreads();
    {
        float4* __restrict__ d0 =
            reinterpret_cast<float4*>(cur1 + ((size_t)t0 * BATCH + b0) * N_HID);
        float4* __restrict__ d1 =
            reinterpret_cast<float4*>(cur1 + ((size_t)(t0 + 1) * BATCH + b0) * N_HID);
        #pragma unroll
        for (int ii = 0; ii < 4; ++ii) {
            const int i = ii * 256 + threadIdx.x;
            const int row = i / 16, g = i % 16;
            d0[i] = *reinterpret_cast<const float4*>(&sm[row * 68 + g * 4]);
            d1[i] = *reinterpret_cast<const float4*>(&sm[4352 + row * 68 + g * 4]);
        }
    }
}

// ---------------- K2: layer-1 recurrence -> BITPACKED spikes ---- (R19 verbatim)
__global__ __launch_bounds__(64) void k2_rec1(
    const float* __restrict__ cs,            // cur1 in outs
    unsigned long long* __restrict__ masks)  // (T,B) u64, in outs tail
{
    const int b = blockIdx.x;
    const int h = threadIdx.x;
    const size_t str  = (size_t)BATCH * N_HID;
    const size_t base = (size_t)b * N_HID + h;

    float A[CH], Bv[CH];
    #pragma unroll
    for (int i = 0; i < CH; ++i) A[i] = cs[(size_t)i * str + base];

    float mem = 0.f, s = 0.f;
    unsigned mlo = 0u, mhi = 0u;     // lane h holds mask of step chunk*50+h
    for (int cp = 0; cp < 5; ++cp) {            // 10 chunks, processed in pairs
        const int c0 = 2 * cp;
        #pragma unroll
        for (int i = 0; i < CH; ++i)            // prefetch chunk c0+1
            Bv[i] = cs[(size_t)((c0 + 1) * CH + i) * str + base];
        #pragma unroll
        for (int i = 0; i < CH; ++i) {          // compute chunk c0 from A
            const float m = __fsub_rn(__fadd_rn(__fmul_rn(0.95f, mem), A[i]), s);
            mem = m; s = (m > 1.0f) ? 1.0f : 0.0f;
            const unsigned long long bal = __ballot(m > 1.0f);
            mlo = (h == i) ? (unsigned)bal : mlo;
            mhi = (h == i) ? (unsigned)(bal >> 32) : mhi;
        }
        if (h < CH)                              // one 50-lane store per chunk
            masks[(size_t)(c0 * CH + h) * BATCH + b] =
                ((unsigned long long)mhi << 32) | mlo;
        if (cp < 4) {
            #pragma unroll
            for (int i = 0; i < CH; ++i)        // prefetch chunk c0+2
                A[i] = cs[(size_t)((c0 + 2) * CH + i) * str + base];
        }
        #pragma unroll
        for (int i = 0; i < CH; ++i) {          // compute chunk c0+1 from Bv
            const float m = __fsub_rn(__fadd_rn(__fmul_rn(0.95f, mem), Bv[i]), s);
            mem = m; s = (m > 1.0f) ? 1.0f : 0.0f;
            const unsigned long long bal = __ballot(m > 1.0f);
            mlo = (h == i) ? (unsigned)bal : mlo;
            mhi = (h == i) ? (unsigned)(bal >> 32) : mhi;
        }
        if (h < CH)
            masks[(size_t)((c0 + 1) * CH + h) * BATCH + b] =
                ((unsigned long long)mhi << 32) | mlo;
    }
}

// ---------------- K3: cur2 = spk @ W2 + b2 (mask-driven, P=4) ---- (R19 verbatim)
__global__ __launch_bounds__(256) void k3_cur2(
    const unsigned long long* __restrict__ masks,  // (T,B)
    const float* __restrict__ W2,   // (64,80)
    const float* __restrict__ b2,   // (80)
    float* __restrict__ cur2)       // (T,B,80) = outm region
{
    const int tq   = blockIdx.x >> 2;        // 0..124
    const int b0   = (blockIdx.x & 3) << 6;
    const int t0   = tq * 4;
    const int lane = threadIdx.x & 63;       // = local b
    const int w    = threadIdx.x >> 6;       // wave id
    const int o0   = w * 20;

    __shared__ float ws[64 * 80];            // 20.5 KB, W2 [k][o]

    {
        const float4* __restrict__ srcw = reinterpret_cast<const float4*>(W2);
        #pragma unroll
        for (int ii = 0; ii < 5; ++ii) {
            const int i = ii * 256 + threadIdx.x;
            *reinterpret_cast<float4*>(&ws[i * 4]) = srcw[i];
        }
    }

    unsigned long long mk0, mk1, mk2, mk3;   // per-lane spike masks (4 t's)
    mk0 = masks[(size_t)(t0 + 0) * BATCH + b0 + lane];
    mk1 = masks[(size_t)(t0 + 1) * BATCH + b0 + lane];
    mk2 = masks[(size_t)(t0 + 2) * BATCH + b0 + lane];
    mk3 = masks[(size_t)(t0 + 3) * BATCH + b0 + lane];
    __syncthreads();

    float acc0[20], acc1[20], acc2[20], acc3[20];
    #pragma unroll
    for (int o = 0; o < 20; ++o) {
        acc0[o] = 0.0f; acc1[o] = 0.0f; acc2[o] = 0.0f; acc3[o] = 0.0f;
    }

    #pragma unroll 2
    for (int kg = 0; kg < 16; ++kg) {
        #pragma unroll
        for (int jj = 0; jj < 4; ++jj) {
            const int k = kg * 4 + jj;
            const float4* __restrict__ wr =                 // LDS broadcast
                reinterpret_cast<const float4*>(&ws[k * 80 + o0]);
            const float4 w0 = wr[0], w1 = wr[1], w2 = wr[2], w3 = wr[3], w4 = wr[4];
            const float wv[20] = {w0.x, w0.y, w0.z, w0.w,
                                  w1.x, w1.y, w1.z, w1.w,
                                  w2.x, w2.y, w2.z, w2.w,
                                  w3.x, w3.y, w3.z, w3.w,
                                  w4.x, w4.y, w4.z, w4.w};
            // sf in {0.0f, 1.0f}: FMA bitwise == FMA with stored spike float
            const float s0 = (float)((mk0 >> k) & 1ULL);
            const float s1 = (float)((mk1 >> k) & 1ULL);
            const float s2 = (float)((mk2 >> k) & 1ULL);
            const float s3 = (float)((mk3 >> k) & 1ULL);
            #pragma unroll
            for (int o = 0; o < 20; ++o) {
                acc0[o] = __fmaf_rn(s0, wv[o], acc0[o]);
                acc1[o] = __fmaf_rn(s1, wv[o], acc1[o]);
                acc2[o] = __fmaf_rn(s2, wv[o], acc2[o]);
                acc3[o] = __fmaf_rn(s3, wv[o], acc3[o]);
            }
        }
    }

    #pragma unroll
    for (int o4 = 0; o4 < 5; ++o4) {
        const float bb0 = b2[o0 + o4 * 4 + 0], bb1 = b2[o0 + o4 * 4 + 1];
        const float bb2 = b2[o0 + o4 * 4 + 2], bb3 = b2[o0 + o4 * 4 + 3];
        float4 v;
        float* d;
        v.x = __fadd_rn(acc0[o4 * 4 + 0], bb0);
        v.y = __fadd_rn(acc0[o4 * 4 + 1], bb1);
        v.z = __fadd_rn(acc0[o4 * 4 + 2], bb2);
        v.w = __fadd_rn(acc0[o4 * 4 + 3], bb3);
        d = cur2 + ((size_t)(t0 + 0) * BATCH + b0 + lane) * N_OUT + o0;
        reinterpret_cast<float4*>(d)[o4] = v;
        v.x = __fadd_rn(acc1[o4 * 4 + 0], bb0);
        v.y = __fadd_rn(acc1[o4 * 4 + 1], bb1);
        v.z = __fadd_rn(acc1[o4 * 4 + 2], bb2);
        v.w = __fadd_rn(acc1[o4 * 4 + 3], bb3);
        d = cur2 + ((size_t)(t0 + 1) * BATCH + b0 + lane) * N_OUT + o0;
        reinterpret_cast<float4*>(d)[o4] = v;
        v.x = __fadd_rn(acc2[o4 * 4 + 0], bb0);
        v.y = __fadd_rn(acc2[o4 * 4 + 1], bb1);
        v.z = __fadd_rn(acc2[o4 * 4 + 2], bb2);
        v.w = __fadd_rn(acc2[o4 * 4 + 3], bb3);
        d = cur2 + ((size_t)(t0 + 2) * BATCH + b0 + lane) * N_OUT + o0;
        reinterpret_cast<float4*>(d)[o4] = v;
        v.x = __fadd_rn(acc3[o4 * 4 + 0], bb0);
        v.y = __fadd_rn(acc3[o4 * 4 + 1], bb1);
        v.z = __fadd_rn(acc3[o4 * 4 + 2], bb2);
        v.w = __fadd_rn(acc3[o4 * 4 + 3], bb3);
        d = cur2 + ((size_t)(t0 + 3) * BATCH + b0 + lane) * N_OUT + o0;
        reinterpret_cast<float4*>(d)[o4] = v;
    }
}

// ---------------- K4: layer-2 recurrence (cur2 in outm -> spk/mem finals) ----------------
__global__ __launch_bounds__(80) void k4_rec2(float* cm, float* os)
{
    const int b = blockIdx.x;
    const int o = threadIdx.x;   // 0..79
    const size_t str  = (size_t)BATCH * N_OUT;
    const size_t base = (size_t)b * N_OUT + o;

    float A[CH], Bv[CH];
    #pragma unroll
    for (int i = 0; i < CH; ++i) A[i] = cm[(size_t)i * str + base];

    float mem = 0.f, s = 0.f;
    for (int cp = 0; cp < 5; ++cp) {
        const int c0 = 2 * cp;
        #pragma unroll
        for (int i = 0; i < CH; ++i)
            Bv[i] = cm[(size_t)((c0 + 1) * CH + i) * str + base];
        #pragma unroll
        for (int i = 0; i < CH; ++i) {
            const int t = c0 * CH + i;
            const float m = __fsub_rn(__fadd_rn(__fmul_rn(0.95f, mem), A[i]), s);
            mem = m; s = (m > 1.0f) ? 1.0f : 0.0f;
            os[(size_t)t * str + base] = s;
            cm[(size_t)t * str + base] = m;
        }
        if (cp < 4) {
            #pragma unroll
            for (int i = 0; i < CH; ++i)
                A[i] = cm[(size_t)((c0 + 2) * CH + i) * str + base];
        }
        #pragma unroll
        for (int i = 0; i < CH; ++i) {
            const int t = (c0 + 1) * CH + i;
            const float m = __fsub_rn(__fadd_rn(__fmul_rn(0.95f, mem), Bv[i]), s);
            mem = m; s = (m > 1.0f) ? 1.0f : 0.0f;
            os[(size_t)t * str + base] = s;
            cm[(size_t)t * str + base] = m;
        }
    }
}

extern "C" void kernel_launch(void* const* d_in, const int* in_sizes, int n_in,
                              void* d_out, int out_size, void* d_ws, size_t ws_size,
                              hipStream_t stream) {
    const float* x  = (const float*)d_in[0];
    const float* W1 = (const float*)d_in[1];
    const float* b1 = (const float*)d_in[2];
    const float* W2 = (const float*)d_in[3];
    const float* b2 = (const float*)d_in[4];
    float* outs = (float*)d_out;                                   // (T,B,80) spikes
    float* outm = outs + (size_t)T_STEPS * BATCH * N_OUT;          // (T,B,80) mem
    unsigned long long* masks =
        (unsigned long long*)(outs + MASK_OFF);                    // 1MB in outs tail

    k1_cur1<<<250 * 4, 256, 0, stream>>>(x, W1, b1, outs);         // cur1 -> outs
    k2_rec1<<<BATCH, 64, 0, stream>>>(outs, masks);                // masks -> outs tail
    k3_cur2<<<125 * 4, 256, 0, stream>>>(masks, W2, b2, outm);     // cur2 -> outm
    k4_rec2<<<BATCH, 80, 0, stream>>>(outm, outs);                 // finals in place
}

// Round 22
// 97.166 us; speedup vs baseline: 1.0348x; 1.0348x over previous
//
#include <hip/hip_runtime.h>

// SNN classifier: T=500, B=256, 96 -> 64 -> 80, leaky (subtract reset).
// f32 BLAS-order arithmetic replicated exactly (single-accumulator
// k-ascending __fmaf_rn chains; fixed leaky op-sequence) -> outputs
// bitwise-identical to all passing kernels this session.
//
// Round-22 = ROUND-16 VERBATIM: the measured-best configuration (97.0us).
// Plateau lock-in per the pre-declared decision rule (R21 total 100.5 >=
// 97). Six K1 variants (P=1/2/4 static, P=2/4 chunked, 2-3 blocks/CU) all
// land 45-52us: the broadcast/occupancy/latency tradeoff surface is
// exhausted. Structure: K1 ~45us (DS-throughput+latency at LDS-feasible
// occupancy), K2 ~10, K3 ~6 (would-be; this config's K3 ~27), K4 ~20
// (>=80% of its HBM roofline), + serial launch gaps.
//
//   K1: P=2 t-pair, 75.8KB static LDS (x 2x[64][100] + full W1), 4-wave
//       blocks (wave = h-quarter), DS-only inner loop (W1 broadcasts +
//       per-lane x rows), transpose-via-LDS linear stores.
//   K2: in-place leaky recurrence, 50-step register double-buffer.
//   K3: P=2 t-pair, spk 2x[64][68] + full W2 (55.3KB), same DS-only form.
//   K4: layer-2 recurrence, finals in place.

#define T_STEPS 500
#define BATCH   256
#define N_IN    96
#define N_HID   64
#define N_OUT   80
#define CH      50    // chunk size in K2/K4 (500 = 10*50)

// ---------------- K1: cur1 = x @ W1 + b1 ----------------
// grid 250*4, block 256 (4 waves = 4 h-quarters). Block = (t-pair, 64-b).
// LDS: x t0 [64][100] @0, x t1 @6400, W1 [96][64] @12800 = 18944 fl = 75.8KB.
__global__ __launch_bounds__(256) void k1_cur1(
    const float* __restrict__ x,   // (T,B,96)
    const float* __restrict__ W1,  // (96,64)
    const float* __restrict__ b1,  // (64)
    float* __restrict__ cur1)      // (T,B,64) region inside outs
{
    const int tp   = blockIdx.x >> 2;        // 0..249
    const int b0   = (blockIdx.x & 3) << 6;
    const int t0   = tp * 2;
    const int lane = threadIdx.x & 63;       // = local b
    const int w    = threadIdx.x >> 6;       // wave id = h-quarter
    const int o0   = w << 4;

    __shared__ float sm[18944];              // 75.8 KB (gfx950: 160KB/CU)

    // ---- stage both x tiles + full W1 (all coalesced, single phase)
    {
        const float4* __restrict__ s0 =
            reinterpret_cast<const float4*>(x + ((size_t)t0 * BATCH + b0) * N_IN);
        const float4* __restrict__ s1 =
            reinterpret_cast<const float4*>(x + ((size_t)(t0 + 1) * BATCH + b0) * N_IN);
        #pragma unroll
        for (int ii = 0; ii < 6; ++ii) {
            const int i = ii * 256 + threadIdx.x;
            const float4 v0 = s0[i], v1 = s1[i];
            const int row = i / 24, g = i % 24;
            *reinterpret_cast<float4*>(&sm[row * 100 + g * 4]) = v0;
            *reinterpret_cast<float4*>(&sm[6400 + row * 100 + g * 4]) = v1;
        }
        const float4* __restrict__ srcw = reinterpret_cast<const float4*>(W1);
        #pragma unroll
        for (int ii = 0; ii < 6; ++ii) {
            const int i = ii * 256 + threadIdx.x;
            *reinterpret_cast<float4*>(&sm[12800 + i * 4]) = srcw[i];
        }
    }
    __syncthreads();

    float acc0[16], acc1[16];
    #pragma unroll
    for (int o = 0; o < 16; ++o) { acc0[o] = 0.0f; acc1[o] = 0.0f; }

    const int xb = lane * 100;
    #pragma unroll 2
    for (int kg = 0; kg < 24; ++kg) {
        const float4 xv0 = *reinterpret_cast<const float4*>(&sm[xb + kg * 4]);
        const float4 xv1 = *reinterpret_cast<const float4*>(&sm[6400 + xb + kg * 4]);
        const float xq0[4] = {xv0.x, xv0.y, xv0.z, xv0.w};
        const float xq1[4] = {xv1.x, xv1.y, xv1.z, xv1.w};
        #pragma unroll
        for (int jj = 0; jj < 4; ++jj) {
            const int k = kg * 4 + jj;
            const float4* __restrict__ wr =                 // LDS broadcast
                reinterpret_cast<const float4*>(&sm[12800 + k * 64 + o0]);
            const float4 w0 = wr[0], w1 = wr[1], w2 = wr[2], w3 = wr[3];
            const float xs0 = xq0[jj], xs1 = xq1[jj];
            acc0[0]  = __fmaf_rn(xs0, w0.x, acc0[0]);
            acc0[1]  = __fmaf_rn(xs0, w0.y, acc0[1]);
            acc0[2]  = __fmaf_rn(xs0, w0.z, acc0[2]);
            acc0[3]  = __fmaf_rn(xs0, w0.w, acc0[3]);
            acc0[4]  = __fmaf_rn(xs0, w1.x, acc0[4]);
            acc0[5]  = __fmaf_rn(xs0, w1.y, acc0[5]);
            acc0[6]  = __fmaf_rn(xs0, w1.z, acc0[6]);
            acc0[7]  = __fmaf_rn(xs0, w1.w, acc0[7]);
            acc0[8]  = __fmaf_rn(xs0, w2.x, acc0[8]);
            acc0[9]  = __fmaf_rn(xs0, w2.y, acc0[9]);
            acc0[10] = __fmaf_rn(xs0, w2.z, acc0[10]);
            acc0[11] = __fmaf_rn(xs0, w2.w, acc0[11]);
            acc0[12] = __fmaf_rn(xs0, w3.x, acc0[12]);
            acc0[13] = __fmaf_rn(xs0, w3.y, acc0[13]);
            acc0[14] = __fmaf_rn(xs0, w3.z, acc0[14]);
            acc0[15] = __fmaf_rn(xs0, w3.w, acc0[15]);
            acc1[0]  = __fmaf_rn(xs1, w0.x, acc1[0]);
            acc1[1]  = __fmaf_rn(xs1, w0.y, acc1[1]);
            acc1[2]  = __fmaf_rn(xs1, w0.z, acc1[2]);
            acc1[3]  = __fmaf_rn(xs1, w0.w, acc1[3]);
            acc1[4]  = __fmaf_rn(xs1, w1.x, acc1[4]);
            acc1[5]  = __fmaf_rn(xs1, w1.y, acc1[5]);
            acc1[6]  = __fmaf_rn(xs1, w1.z, acc1[6]);
            acc1[7]  = __fmaf_rn(xs1, w1.w, acc1[7]);
            acc1[8]  = __fmaf_rn(xs1, w2.x, acc1[8]);
            acc1[9]  = __fmaf_rn(xs1, w2.y, acc1[9]);
            acc1[10] = __fmaf_rn(xs1, w2.z, acc1[10]);
            acc1[11] = __fmaf_rn(xs1, w2.w, acc1[11]);
            acc1[12] = __fmaf_rn(xs1, w3.x, acc1[12]);
            acc1[13] = __fmaf_rn(xs1, w3.y, acc1[13]);
            acc1[14] = __fmaf_rn(xs1, w3.z, acc1[14]);
            acc1[15] = __fmaf_rn(xs1, w3.w, acc1[15]);
        }
    }

    // ---- bias, transpose both t's via LDS (reuse x areas), linear stores
    __syncthreads();                     // all x/W reads done
    #pragma unroll
    for (int o4 = 0; o4 < 4; ++o4) {
        float4 v0, v1;
        v0.x = __fadd_rn(acc0[o4 * 4 + 0], b1[o0 + o4 * 4 + 0]);
        v0.y = __fadd_rn(acc0[o4 * 4 + 1], b1[o0 + o4 * 4 + 1]);
        v0.z = __fadd_rn(acc0[o4 * 4 + 2], b1[o0 + o4 * 4 + 2]);
        v0.w = __fadd_rn(acc0[o4 * 4 + 3], b1[o0 + o4 * 4 + 3]);
        v1.x = __fadd_rn(acc1[o4 * 4 + 0], b1[o0 + o4 * 4 + 0]);
        v1.y = __fadd_rn(acc1[o4 * 4 + 1], b1[o0 + o4 * 4 + 1]);
        v1.z = __fadd_rn(acc1[o4 * 4 + 2], b1[o0 + o4 * 4 + 2]);
        v1.w = __fadd_rn(acc1[o4 * 4 + 3], b1[o0 + o4 * 4 + 3]);
        *reinterpret_cast<float4*>(&sm[lane * 68 + o0 + o4 * 4]) = v0;
        *reinterpret_cast<float4*>(&sm[6400 + lane * 68 + o0 + o4 * 4]) = v1;
    }
    __syncthreads();
    {
        float4* __restrict__ d0 =
            reinterpret_cast<float4*>(cur1 + ((size_t)t0 * BATCH + b0) * N_HID);
        float4* __restrict__ d1 =
            reinterpret_cast<float4*>(cur1 + ((size_t)(t0 + 1) * BATCH + b0) * N_HID);
        #pragma unroll
        for (int ii = 0; ii < 4; ++ii) {
            const int i = ii * 256 + threadIdx.x;
            const int row = i / 16, g = i % 16;
            d0[i] = *reinterpret_cast<const float4*>(&sm[row * 68 + g * 4]);
            d1[i] = *reinterpret_cast<const float4*>(&sm[6400 + row * 68 + g * 4]);
        }
    }
}

// ---------------- K2: layer-1 recurrence (in-place cur1 -> spk) ----------------
__global__ __launch_bounds__(64) void k2_rec1(float* cs)  // outs region
{
    const int b = blockIdx.x;
    const int h = threadIdx.x;
    const size_t str  = (size_t)BATCH * N_HID;
    const size_t base = (size_t)b * N_HID + h;

    float A[CH], Bv[CH];
    #pragma unroll
    for (int i = 0; i < CH; ++i) A[i] = cs[(size_t)i * str + base];

    float mem = 0.f, s = 0.f;
    for (int cp = 0; cp < 5; ++cp) {            // 10 chunks, processed in pairs
        const int c0 = 2 * cp;
        #pragma unroll
        for (int i = 0; i < CH; ++i)            // prefetch chunk c0+1
            Bv[i] = cs[(size_t)((c0 + 1) * CH + i) * str + base];
        #pragma unroll
        for (int i = 0; i < CH; ++i) {          // compute chunk c0 from A
            const float m = __fsub_rn(__fadd_rn(__fmul_rn(0.95f, mem), A[i]), s);
            mem = m; s = (m > 1.0f) ? 1.0f : 0.0f;
            cs[(size_t)(c0 * CH + i) * str + base] = s;
        }
        if (cp < 4) {
            #pragma unroll
            for (int i = 0; i < CH; ++i)        // prefetch chunk c0+2
                A[i] = cs[(size_t)((c0 + 2) * CH + i) * str + base];
        }
        #pragma unroll
        for (int i = 0; i < CH; ++i) {          // compute chunk c0+1 from Bv
            const float m = __fsub_rn(__fadd_rn(__fmul_rn(0.95f, mem), Bv[i]), s);
            mem = m; s = (m > 1.0f) ? 1.0f : 0.0f;
            cs[(size_t)((c0 + 1) * CH + i) * str + base] = s;
        }
    }
}

// ---------------- K3: cur2 = spk @ W2 + b2 ----------------
// grid 250*4, block 256 (4 waves = 4 20-o slices). Block = (t-pair, 64-b).
// LDS: spk 2x[64][68] @0 (8704 dw) + W2 [64][80] @8704 (5120 dw) = 55.3 KB.
__global__ __launch_bounds__(256) void k3_cur2(
    const float* __restrict__ spk,  // (T,B,64) in outs
    const float* __restrict__ W2,   // (64,80)
    const float* __restrict__ b2,   // (80)
    float* __restrict__ cur2)       // (T,B,80) = outm region
{
    const int tp   = blockIdx.x >> 2;
    const int b0   = (blockIdx.x & 3) << 6;
    const int t0   = tp * 2;
    const int lane = threadIdx.x & 63;   // = local b
    const int w    = threadIdx.x >> 6;   // wave id
    const int o0   = w * 20;

    __shared__ float sm[13824];          // 55.3 KB

    // ---- stage spk tiles (coalesced) + full W2 (coalesced, linear)
    {
        const float4* __restrict__ s0 =
            reinterpret_cast<const float4*>(spk + ((size_t)t0 * BATCH + b0) * N_HID);
        const float4* __restrict__ s1 =
            reinterpret_cast<const float4*>(spk + ((size_t)(t0 + 1) * BATCH + b0) * N_HID);
        #pragma unroll
        for (int ii = 0; ii < 4; ++ii) {
            const int i = ii * 256 + threadIdx.x;
            const float4 v0 = s0[i], v1 = s1[i];
            const int row = i / 16, g = i % 16;
            *reinterpret_cast<float4*>(&sm[row * 68 + g * 4]) = v0;
            *reinterpret_cast<float4*>(&sm[4352 + row * 68 + g * 4]) = v1;
        }
        const float4* __restrict__ srcw = reinterpret_cast<const float4*>(W2);
        for (int i = threadIdx.x; i < 1280; i += 256)
            *reinterpret_cast<float4*>(&sm[8704 + i * 4]) = srcw[i];
    }
    __syncthreads();

    float acc0[20], acc1[20];
    #pragma unroll
    for (int o = 0; o < 20; ++o) { acc0[o] = 0.0f; acc1[o] = 0.0f; }

    const int xb0 = lane * 68;
    const int xb1 = 4352 + lane * 68;
    #pragma unroll 2
    for (int kg = 0; kg < 16; ++kg) {
        const float4 xv0 = *reinterpret_cast<const float4*>(&sm[xb0 + kg * 4]);
        const float4 xv1 = *reinterpret_cast<const float4*>(&sm[xb1 + kg * 4]);
        const float xq0[4] = {xv0.x, xv0.y, xv0.z, xv0.w};
        const float xq1[4] = {xv1.x, xv1.y, xv1.z, xv1.w};
        #pragma unroll
        for (int jj = 0; jj < 4; ++jj) {
            const int k = kg * 4 + jj;
            const float4* __restrict__ wr =                 // LDS broadcast
                reinterpret_cast<const float4*>(&sm[8704 + k * 80 + o0]);
            const float4 w0 = wr[0], w1 = wr[1], w2 = wr[2], w3 = wr[3], w4 = wr[4];
            const float a = xq0[jj], b = xq1[jj];
            acc0[0]  = __fmaf_rn(a, w0.x, acc0[0]);
            acc0[1]  = __fmaf_rn(a, w0.y, acc0[1]);
            acc0[2]  = __fmaf_rn(a, w0.z, acc0[2]);
            acc0[3]  = __fmaf_rn(a, w0.w, acc0[3]);
            acc0[4]  = __fmaf_rn(a, w1.x, acc0[4]);
            acc0[5]  = __fmaf_rn(a, w1.y, acc0[5]);
            acc0[6]  = __fmaf_rn(a, w1.z, acc0[6]);
            acc0[7]  = __fmaf_rn(a, w1.w, acc0[7]);
            acc0[8]  = __fmaf_rn(a, w2.x, acc0[8]);
            acc0[9]  = __fmaf_rn(a, w2.y, acc0[9]);
            acc0[10] = __fmaf_rn(a, w2.z, acc0[10]);
            acc0[11] = __fmaf_rn(a, w2.w, acc0[11]);
            acc0[12] = __fmaf_rn(a, w3.x, acc0[12]);
            acc0[13] = __fmaf_rn(a, w3.y, acc0[13]);
            acc0[14] = __fmaf_rn(a, w3.z, acc0[14]);
            acc0[15] = __fmaf_rn(a, w3.w, acc0[15]);
            acc0[16] = __fmaf_rn(a, w4.x, acc0[16]);
            acc0[17] = __fmaf_rn(a, w4.y, acc0[17]);
            acc0[18] = __fmaf_rn(a, w4.z, acc0[18]);
            acc0[19] = __fmaf_rn(a, w4.w, acc0[19]);
            acc1[0]  = __fmaf_rn(b, w0.x, acc1[0]);
            acc1[1]  = __fmaf_rn(b, w0.y, acc1[1]);
            acc1[2]  = __fmaf_rn(b, w0.z, acc1[2]);
            acc1[3]  = __fmaf_rn(b, w0.w, acc1[3]);
            acc1[4]  = __fmaf_rn(b, w1.x, acc1[4]);
            acc1[5]  = __fmaf_rn(b, w1.y, acc1[5]);
            acc1[6]  = __fmaf_rn(b, w1.z, acc1[6]);
            acc1[7]  = __fmaf_rn(b, w1.w, acc1[7]);
            acc1[8]  = __fmaf_rn(b, w2.x, acc1[8]);
            acc1[9]  = __fmaf_rn(b, w2.y, acc1[9]);
            acc1[10] = __fmaf_rn(b, w2.z, acc1[10]);
            acc1[11] = __fmaf_rn(b, w2.w, acc1[11]);
            acc1[12] = __fmaf_rn(b, w3.x, acc1[12]);
            acc1[13] = __fmaf_rn(b, w3.y, acc1[13]);
            acc1[14] = __fmaf_rn(b, w3.z, acc1[14]);
            acc1[15] = __fmaf_rn(b, w3.w, acc1[15]);
            acc1[16] = __fmaf_rn(b, w4.x, acc1[16]);
            acc1[17] = __fmaf_rn(b, w4.y, acc1[17]);
            acc1[18] = __fmaf_rn(b, w4.z, acc1[18]);
            acc1[19] = __fmaf_rn(b, w4.w, acc1[19]);
        }
    }

    // ---- bias, transpose via LDS, linear block stores
    __syncthreads();                     // all spk/W reads done
    #pragma unroll
    for (int o4 = 0; o4 < 5; ++o4) {
        float4 v0, v1;
        v0.x = __fadd_rn(acc0[o4 * 4 + 0], b2[o0 + o4 * 4 + 0]);
        v0.y = __fadd_rn(acc0[o4 * 4 + 1], b2[o0 + o4 * 4 + 1]);
        v0.z = __fadd_rn(acc0[o4 * 4 + 2], b2[o0 + o4 * 4 + 2]);
        v0.w = __fadd_rn(acc0[o4 * 4 + 3], b2[o0 + o4 * 4 + 3]);
        v1.x = __fadd_rn(acc1[o4 * 4 + 0], b2[o0 + o4 * 4 + 0]);
        v1.y = __fadd_rn(acc1[o4 * 4 + 1], b2[o0 + o4 * 4 + 1]);
        v1.z = __fadd_rn(acc1[o4 * 4 + 2], b2[o0 + o4 * 4 + 2]);
        v1.w = __fadd_rn(acc1[o4 * 4 + 3], b2[o0 + o4 * 4 + 3]);
        *reinterpret_cast<float4*>(&sm[lane * 84 + o0 + o4 * 4]) = v0;
        *reinterpret_cast<float4*>(&sm[5376 + lane * 84 + o0 + o4 * 4]) = v1;
    }
    __syncthreads();
    {
        float4* __restrict__ d0 =
            reinterpret_cast<float4*>(cur2 + ((size_t)t0 * BATCH + b0) * N_OUT);
        float4* __restrict__ d1 =
            reinterpret_cast<float4*>(cur2 + ((size_t)(t0 + 1) * BATCH + b0) * N_OUT);
        #pragma unroll
        for (int ii = 0; ii < 5; ++ii) {
            const int i = ii * 256 + threadIdx.x;
            const int row = i / 20, g = i % 20;
            d0[i] = *reinterpret_cast<const float4*>(&sm[row * 84 + g * 4]);
            d1[i] = *reinterpret_cast<const float4*>(&sm[5376 + row * 84 + g * 4]);
        }
    }
}

// ---------------- K4: layer-2 recurrence (cur2 in outm -> spk/mem finals) ----------------
__global__ __launch_bounds__(80) void k4_rec2(float* cm, float* os)
{
    const int b = blockIdx.x;
    const int o = threadIdx.x;   // 0..79
    const size_t str  = (size_t)BATCH * N_OUT;
    const size_t base = (size_t)b * N_OUT + o;

    float A[CH], Bv[CH];
    #pragma unroll
    for (int i = 0; i < CH; ++i) A[i] = cm[(size_t)i * str + base];

    float mem = 0.f, s = 0.f;
    for (int cp = 0; cp < 5; ++cp) {
        const int c0 = 2 * cp;
        #pragma unroll
        for (int i = 0; i < CH; ++i)
            Bv[i] = cm[(size_t)((c0 + 1) * CH + i) * str + base];
        #pragma unroll
        for (int i = 0; i < CH; ++i) {
            const int t = c0 * CH + i;
            const float m = __fsub_rn(__fadd_rn(__fmul_rn(0.95f, mem), A[i]), s);
            mem = m; s = (m > 1.0f) ? 1.0f : 0.0f;
            os[(size_t)t * str + base] = s;
            cm[(size_t)t * str + base] = m;
        }
        if (cp < 4) {
            #pragma unroll
            for (int i = 0; i < CH; ++i)
                A[i] = cm[(size_t)((c0 + 2) * CH + i) * str + base];
        }
        #pragma unroll
        for (int i = 0; i < CH; ++i) {
            const int t = (c0 + 1) * CH + i;
            const float m = __fsub_rn(__fadd_rn(__fmul_rn(0.95f, mem), Bv[i]), s);
            mem = m; s = (m > 1.0f) ? 1.0f : 0.0f;
            os[(size_t)t * str + base] = s;
            cm[(size_t)t * str + base] = m;
        }
    }
}

extern "C" void kernel_launch(void* const* d_in, const int* in_sizes, int n_in,
                              void* d_out, int out_size, void* d_ws, size_t ws_size,
                              hipStream_t stream) {
    const float* x  = (const float*)d_in[0];
    const float* W1 = (const float*)d_in[1];
    const float* b1 = (const float*)d_in[2];
    const float* W2 = (const float*)d_in[3];
    const float* b2 = (const float*)d_in[4];
    float* outs = (float*)d_out;                                   // (T,B,80) spikes
    float* outm = outs + (size_t)T_STEPS * BATCH * N_OUT;          // (T,B,80) mem

    k1_cur1<<<250 * 4, 256, 0, stream>>>(x, W1, b1, outs);         // cur1 -> outs
    k2_rec1<<<BATCH, 64, 0, stream>>>(outs);                       // spk overwrites cur1
    k3_cur2<<<250 * 4, 256, 0, stream>>>(outs, W2, b2, outm);      // cur2 -> outm
    k4_rec2<<<BATCH, 80, 0, stream>>>(outm, outs);                 // finals in place
}